// Round 1
// baseline (1080.870 us; speedup 1.0000x reference)
//
#include <hip/hip_runtime.h>
#include <math.h>

#define NPTS   65536
#define DIM    128
#define KCODES 4096

constexpr float DECAY_F         = 0.99f;
constexpr float ONE_MINUS_DECAY = 0.01f;
constexpr float EPS_F           = 1e-5f;

// d_out layout (floats): quantize_st[N*D] | embed_ind[N] | loss[1] | new_embed[K*D] | new_cluster_size[K]
constexpr int OFF_IDX  = NPTS * DIM;             // 8388608
constexpr int OFF_LOSS = OFF_IDX + NPTS;         // 8454144
constexpr int OFF_EMB  = OFF_LOSS + 1;           // 8454145
constexpr int OFF_NCS  = OFF_EMB + KCODES * DIM; // 8978433

// ---------------- e_sq precompute: one wave per code ----------------
__global__ __launch_bounds__(256) void vq_esq_kernel(const float* __restrict__ embed,
                                                     float* __restrict__ esq) {
    int tid  = threadIdx.x;
    int k    = blockIdx.x * 4 + (tid >> 6);
    int lane = tid & 63;
    float v0 = embed[k * DIM + lane];
    float v1 = embed[k * DIM + 64 + lane];
    float s  = v0 * v0 + v1 * v1;
#pragma unroll
    for (int off = 32; off >= 1; off >>= 1) s += __shfl_down(s, off);
    if (lane == 0) esq[k] = s;
}

// ---------------- main: distance argmin + fused gather/scatter epilogue ----------------
// block = 256 threads (16 tx x 16 ty); tile = 64 rows x 64 codes; 4x4 acc per thread.
#define DOT4(ACC, A, B) \
    ACC = fmaf((A).x, (B).x, fmaf((A).y, (B).y, fmaf((A).z, (B).z, fmaf((A).w, (B).w, ACC))))

__global__ __launch_bounds__(256, 2)
void vq_main_kernel(const float* __restrict__ x, const float* __restrict__ embed,
                    const float* __restrict__ esq, float* __restrict__ out) {
    __shared__ float4 Xs4[64 * 33];   // [row][33 f4], rows padded 128->132 floats
    __shared__ float4 Es4[64 * 33];   // same, but d4-granule XOR-swizzled by (row>>2)
    __shared__ int    idx_s[64];
    __shared__ float  red[256];

    float* out_q   = out;
    float* out_idx = out + OFF_IDX;
    float* loss_p  = out + OFF_LOSS;
    float* emb_acc = out + OFF_EMB;
    float* ncs_acc = out + OFF_NCS;

    const int tid  = threadIdx.x;
    const int tx   = tid & 15;
    const int ty   = tid >> 4;
    const int row0 = blockIdx.x * 64;

    // stage X tile (64x128), coalesced float4, kept resident for the whole block
    {
        const float4* xg = (const float4*)(x + (size_t)row0 * DIM);
#pragma unroll
        for (int it = 0; it < 8; ++it) {
            int i4 = tid + it * 256;           // 0..2047
            int r = i4 >> 5, d4 = i4 & 31;
            Xs4[r * 33 + d4] = xg[i4];
        }
    }

    float minv[4] = {3.4e38f, 3.4e38f, 3.4e38f, 3.4e38f};
    int   mini[4] = {0, 0, 0, 0};

    for (int kt = 0; kt < 64; ++kt) {
        __syncthreads();   // protect Es from previous iteration's readers
        {
            const float4* eg = (const float4*)(embed + (size_t)(kt * 64) * DIM);
#pragma unroll
            for (int it = 0; it < 8; ++it) {
                int i4 = tid + it * 256;
                int r = i4 >> 5, d4 = i4 & 31;
                Es4[r * 33 + (d4 ^ (r >> 2))] = eg[i4];   // XOR-swizzled store
            }
        }
        __syncthreads();

        float acc[4][4];
#pragma unroll
        for (int r = 0; r < 4; ++r)
#pragma unroll
            for (int c = 0; c < 4; ++c) acc[r][c] = 0.f;

#pragma unroll 4
        for (int d4 = 0; d4 < 32; ++d4) {
            float4 a0 = Xs4[(4 * ty + 0) * 33 + d4];
            float4 a1 = Xs4[(4 * ty + 1) * 33 + d4];
            float4 a2 = Xs4[(4 * ty + 2) * 33 + d4];
            float4 a3 = Xs4[(4 * ty + 3) * 33 + d4];
            int bswz = d4 ^ tx;                           // matches store swizzle (row>>2 == tx)
            float4 b0 = Es4[(4 * tx + 0) * 33 + bswz];
            float4 b1 = Es4[(4 * tx + 1) * 33 + bswz];
            float4 b2 = Es4[(4 * tx + 2) * 33 + bswz];
            float4 b3 = Es4[(4 * tx + 3) * 33 + bswz];
            DOT4(acc[0][0], a0, b0); DOT4(acc[0][1], a0, b1); DOT4(acc[0][2], a0, b2); DOT4(acc[0][3], a0, b3);
            DOT4(acc[1][0], a1, b0); DOT4(acc[1][1], a1, b1); DOT4(acc[1][2], a1, b2); DOT4(acc[1][3], a1, b3);
            DOT4(acc[2][0], a2, b0); DOT4(acc[2][1], a2, b1); DOT4(acc[2][2], a2, b2); DOT4(acc[2][3], a2, b3);
            DOT4(acc[3][0], a3, b0); DOT4(acc[3][1], a3, b1); DOT4(acc[3][2], a3, b2); DOT4(acc[3][3], a3, b3);
        }

        // score = |e|^2 - 2*x.e  (x^2 constant per row, dropped)
        int kbase = kt * 64 + 4 * tx;
        float e0 = esq[kbase + 0], e1 = esq[kbase + 1], e2 = esq[kbase + 2], e3 = esq[kbase + 3];
#pragma unroll
        for (int r = 0; r < 4; ++r) {
            float s0 = fmaf(-2.f, acc[r][0], e0);
            float s1 = fmaf(-2.f, acc[r][1], e1);
            float s2 = fmaf(-2.f, acc[r][2], e2);
            float s3 = fmaf(-2.f, acc[r][3], e3);
            if (s0 < minv[r]) { minv[r] = s0; mini[r] = kbase + 0; }
            if (s1 < minv[r]) { minv[r] = s1; mini[r] = kbase + 1; }
            if (s2 < minv[r]) { minv[r] = s2; mini[r] = kbase + 2; }
            if (s3 < minv[r]) { minv[r] = s3; mini[r] = kbase + 3; }
        }
    }

    // reduce across the 16 tx lanes sharing each row-quad (lanes i..i+15 within wave)
#pragma unroll
    for (int off = 1; off < 16; off <<= 1) {
#pragma unroll
        for (int r = 0; r < 4; ++r) {
            float v2 = __shfl_xor(minv[r], off);
            int   i2 = __shfl_xor(mini[r], off);
            if (v2 < minv[r] || (v2 == minv[r] && i2 < mini[r])) { minv[r] = v2; mini[r] = i2; }
        }
    }
    if (tx == 0) {
#pragma unroll
        for (int r = 0; r < 4; ++r) {
            int row = 4 * ty + r;
            int k   = mini[r];
            idx_s[row] = k;
            out_idx[row0 + row] = (float)k;
            atomicAdd(&ncs_acc[k], 1.0f);   // counts accumulate into ncs slot
        }
    }
    __syncthreads();

    // fused epilogue: gather quantize, commit-loss partial, embed_sum scatter
    const float* Xs = (const float*)Xs4;
    float lsum = 0.f;
#pragma unroll 4
    for (int it = 0; it < 32; ++it) {
        int i = tid + it * 256;          // 0..8191
        int r = i >> 7, d = i & 127;
        int k = idx_s[r];
        float q  = embed[k * DIM + d];
        float xv = Xs[r * 132 + d];
        out_q[(size_t)(row0 + r) * DIM + d] = q;
        float diff = q - xv;
        lsum = fmaf(diff, diff, lsum);
        atomicAdd(&emb_acc[k * DIM + d], xv);   // embed_sum accumulates into new_embed slot
    }
    red[tid] = lsum;
    __syncthreads();
    for (int s = 128; s >= 1; s >>= 1) {
        if (tid < s) red[tid] += red[tid + s];
        __syncthreads();
    }
    if (tid == 0) atomicAdd(loss_p, red[0]);
}

// ---------------- finalize cluster sizes, n_total, inv_smoothed, loss scale ----------------
__global__ __launch_bounds__(256) void vq_finalize_kernel(const float* __restrict__ cs,
                                                          float* __restrict__ out,
                                                          float* __restrict__ inv_sm) {
    __shared__ float red[256];
    float* ncs    = out + OFF_NCS;    // holds counts on entry
    float* loss_p = out + OFF_LOSS;
    int tid = threadIdx.x;
    float vloc[16];
    float part = 0.f;
#pragma unroll
    for (int it = 0; it < 16; ++it) {
        int k = tid + it * 256;
        float v = fmaf(cs[k], DECAY_F, ncs[k] * ONE_MINUS_DECAY);
        vloc[it] = v;
        ncs[k] = v;                   // in-place: counts -> new_cluster_size
        part += v;
    }
    red[tid] = part;
    __syncthreads();
    for (int s = 128; s >= 1; s >>= 1) {
        if (tid < s) red[tid] += red[tid + s];
        __syncthreads();
    }
    float ntot = red[0];
    float num  = ntot + (float)KCODES * EPS_F;
#pragma unroll
    for (int it = 0; it < 16; ++it) {
        int k = tid + it * 256;
        // smoothed = (ncs+eps)/(ntot+K*eps)*ntot ; store 1/smoothed
        inv_sm[k] = num / ((vloc[it] + EPS_F) * ntot);
    }
    if (tid == 0) loss_p[0] = loss_p[0] * (1.0f / ((float)NPTS * (float)DIM));
}

// ---------------- new_embed = (embed_avg*0.99 + embed_sum*0.01) / smoothed ----------------
__global__ __launch_bounds__(256) void vq_embed_kernel(const float* __restrict__ eavg,
                                                       const float* __restrict__ inv_sm,
                                                       float* __restrict__ out) {
    float* emb = out + OFF_EMB;       // holds embed_sum on entry (region is only 4B-aligned)
    int i = blockIdx.x * 256 + threadIdx.x;
    int k = i >> 7;
    float v = fmaf(eavg[i], DECAY_F, emb[i] * ONE_MINUS_DECAY);
    emb[i] = v * inv_sm[k];
}

extern "C" void kernel_launch(void* const* d_in, const int* in_sizes, int n_in,
                              void* d_out, int out_size, void* d_ws, size_t ws_size,
                              hipStream_t stream) {
    const float* x     = (const float*)d_in[0];
    const float* embed = (const float*)d_in[1];
    const float* cs    = (const float*)d_in[2];
    const float* eavg  = (const float*)d_in[3];
    float* out   = (float*)d_out;
    float* esq   = (float*)d_ws;          // K floats
    float* inv_sm = esq + KCODES;         // K floats

    // zero the accumulator regions (loss + new_embed + ncs are contiguous at the tail)
    hipMemsetAsync(out + OFF_LOSS, 0, (size_t)(1 + KCODES * DIM + KCODES) * sizeof(float), stream);

    vq_esq_kernel<<<KCODES / 4, 256, 0, stream>>>(embed, esq);
    vq_main_kernel<<<NPTS / 64, 256, 0, stream>>>(x, embed, esq, out);
    vq_finalize_kernel<<<1, 256, 0, stream>>>(cs, out, inv_sm);
    vq_embed_kernel<<<(KCODES * DIM) / 256, 256, 0, stream>>>(eavg, inv_sm, out);
}

// Round 2
// 412.861 us; speedup vs baseline: 2.6180x; 2.6180x over previous
//
#include <hip/hip_runtime.h>
#include <math.h>

#define NPTS   65536
#define DIM    128
#define KCODES 4096

constexpr float DECAY_F         = 0.99f;
constexpr float ONE_MINUS_DECAY = 0.01f;
constexpr float EPS_F           = 1e-5f;

// d_out layout (floats): quantize_st[N*D] | embed_ind[N] | loss[1] | new_embed[K*D] | new_cluster_size[K]
constexpr int OFF_IDX  = NPTS * DIM;
constexpr int OFF_LOSS = OFF_IDX + NPTS;
constexpr int OFF_EMB  = OFF_LOSS + 1;
constexpr int OFF_NCS  = OFF_EMB + KCODES * DIM;

typedef _Float16 half8 __attribute__((ext_vector_type(8)));
typedef _Float16 half4 __attribute__((ext_vector_type(4)));
typedef float    f32x4 __attribute__((ext_vector_type(4)));

// ---------------- prep: embed -> f16 hi/lo split + exact fp32 |e|^2 ----------------
__global__ __launch_bounds__(256) void vq_prep_kernel(const float* __restrict__ embed,
                                                      float* __restrict__ esq,
                                                      _Float16* __restrict__ Ehi,
                                                      _Float16* __restrict__ Elo) {
    int tid  = threadIdx.x;
    int k    = blockIdx.x * 4 + (tid >> 6);
    int lane = tid & 63;
    float v0 = embed[k * DIM + lane];
    float v1 = embed[k * DIM + 64 + lane];
    _Float16 h0 = (_Float16)v0, h1 = (_Float16)v1;
    Ehi[k * DIM + lane]      = h0;
    Ehi[k * DIM + 64 + lane] = h1;
    Elo[k * DIM + lane]      = (_Float16)(v0 - (float)h0);
    Elo[k * DIM + 64 + lane] = (_Float16)(v1 - (float)h1);
    float s = v0 * v0 + v1 * v1;
#pragma unroll
    for (int off = 32; off >= 1; off >>= 1) s += __shfl_down(s, off);
    if (lane == 0) esq[k] = s;
}

// ---------------- main: MFMA distance argmin + fused gather/scatter epilogue ----------------
// 256 thr = 4 waves; block tile 128 rows; wave owns 32 rows (2 frags of 16).
// A = -2x in f16 hi/lo, register-resident. E tiles (64 codes) double-buffered in LDS.
// score = esq[k] + sum(A*E)  (x^2 constant per row, dropped).
__global__ __launch_bounds__(256, 2)
void vq_main_kernel(const float* __restrict__ x, const float* __restrict__ embed,
                    const float* __restrict__ esq, const _Float16* __restrict__ Ehi_g,
                    const _Float16* __restrict__ Elo_g, float* __restrict__ out) {
    __shared__ __align__(16) unsigned char lds[65536];
    __shared__ int   idx_s[128];
    __shared__ float red[256];

    float* out_q   = out;
    float* out_idx = out + OFF_IDX;
    float* loss_p  = out + OFF_LOSS;
    float* emb_acc = out + OFF_EMB;
    float* ncs_acc = out + OFF_NCS;

    const int tid  = threadIdx.x;
    const int l    = tid & 63;
    const int w    = tid >> 6;
    const int row0 = blockIdx.x * 128;

    // ---- phase 1: stage A = -2x (f16 hi @0, lo @32768), swizzled rows of 256B ----
    {
        const float4* xg = (const float4*)(x + (size_t)row0 * DIM);
#pragma unroll
        for (int it = 0; it < 16; ++it) {
            int i4 = tid + it * 256;            // 0..4095
            int r = i4 >> 5, c4 = i4 & 31;
            float4 v = xg[i4];
            float m0 = -2.f * v.x, m1 = -2.f * v.y, m2 = -2.f * v.z, m3 = -2.f * v.w;
            half4 h, lo;
            h[0] = (_Float16)m0; h[1] = (_Float16)m1; h[2] = (_Float16)m2; h[3] = (_Float16)m3;
            lo[0] = (_Float16)(m0 - (float)h[0]); lo[1] = (_Float16)(m1 - (float)h[1]);
            lo[2] = (_Float16)(m2 - (float)h[2]); lo[3] = (_Float16)(m3 - (float)h[3]);
            int byteoff = r * 256 + ((c4 * 8) ^ ((r & 7) << 4));
            *(half4*)(lds + byteoff)         = h;
            *(half4*)(lds + 32768 + byteoff) = lo;
        }
    }
    __syncthreads();

    // ---- load A fragments to registers: k-pattern = ks*32 + (l>>4)*8 + j (same as B) ----
    half8 ahi[2][4], alo[2][4];
#pragma unroll
    for (int rf = 0; rf < 2; ++rf)
#pragma unroll
        for (int ks = 0; ks < 4; ++ks) {
            int row = w * 32 + rf * 16 + (l & 15);
            int byteoff = row * 256 + ((ks * 64 + (l >> 4) * 16) ^ ((row & 7) << 4));
            ahi[rf][ks] = *(const half8*)(lds + byteoff);
            alo[rf][ks] = *(const half8*)(lds + 32768 + byteoff);
        }
    __syncthreads();   // X phase done; lds becomes E double-buffer (buf p at p*32768, hi|lo 16KB each)

    half8 sthi[4], stlo[4];   // staging registers (issue-early / write-late)
#define STAGE_REGS(CT)                                                              \
    {                                                                               \
        const half8* gh = (const half8*)(Ehi_g + (size_t)(CT) * 64 * DIM);          \
        const half8* gl = (const half8*)(Elo_g + (size_t)(CT) * 64 * DIM);          \
        _Pragma("unroll")                                                           \
        for (int t = 0; t < 4; ++t) { int i8 = tid + t * 256; sthi[t] = gh[i8]; stlo[t] = gl[i8]; } \
    }
#define WRITE_LDS(P)                                                                \
    {                                                                               \
        unsigned char* bh = lds + (P) * 32768;                                      \
        unsigned char* bl = bh + 16384;                                             \
        _Pragma("unroll")                                                           \
        for (int t = 0; t < 4; ++t) {                                               \
            int i8 = tid + t * 256; int r = i8 >> 4, c8 = i8 & 15;                  \
            int byteoff = r * 256 + ((c8 * 16) ^ ((r & 7) << 4));                   \
            *(half8*)(bh + byteoff) = sthi[t];                                      \
            *(half8*)(bl + byteoff) = stlo[t];                                      \
        }                                                                           \
    }

    float minv[2][4];
    int   mini[2][4];
#pragma unroll
    for (int rf = 0; rf < 2; ++rf)
#pragma unroll
        for (int r = 0; r < 4; ++r) { minv[rf][r] = 3.4e38f; mini[rf][r] = 0; }

    STAGE_REGS(0); WRITE_LDS(0); __syncthreads();
    STAGE_REGS(1);

    for (int ct = 0; ct < 64; ++ct) {
        int p = ct & 1;
        const unsigned char* bhb = lds + p * 32768;
        const unsigned char* blb = bhb + 16384;

        // esq values consumed only at min-update -> latency hides under MFMAs
        float ecf[4];
#pragma unroll
        for (int cf = 0; cf < 4; ++cf) ecf[cf] = esq[ct * 64 + cf * 16 + (l & 15)];

        f32x4 acc[2][4];
#pragma unroll
        for (int rf = 0; rf < 2; ++rf)
#pragma unroll
            for (int cf = 0; cf < 4; ++cf) acc[rf][cf] = (f32x4){0.f, 0.f, 0.f, 0.f};

#pragma unroll
        for (int ks = 0; ks < 4; ++ks) {
#pragma unroll
            for (int cf = 0; cf < 4; ++cf) {
                int row = cf * 16 + (l & 15);
                int byteoff = row * 256 + ((ks * 64 + (l >> 4) * 16) ^ ((row & 7) << 4));
                half8 bh = *(const half8*)(bhb + byteoff);
                half8 bl = *(const half8*)(blb + byteoff);
                acc[0][cf] = __builtin_amdgcn_mfma_f32_16x16x32_f16(ahi[0][ks], bh, acc[0][cf], 0, 0, 0);
                acc[1][cf] = __builtin_amdgcn_mfma_f32_16x16x32_f16(ahi[1][ks], bh, acc[1][cf], 0, 0, 0);
                acc[0][cf] = __builtin_amdgcn_mfma_f32_16x16x32_f16(alo[0][ks], bh, acc[0][cf], 0, 0, 0);
                acc[1][cf] = __builtin_amdgcn_mfma_f32_16x16x32_f16(alo[1][ks], bh, acc[1][cf], 0, 0, 0);
                acc[0][cf] = __builtin_amdgcn_mfma_f32_16x16x32_f16(ahi[0][ks], bl, acc[0][cf], 0, 0, 0);
                acc[1][cf] = __builtin_amdgcn_mfma_f32_16x16x32_f16(ahi[1][ks], bl, acc[1][cf], 0, 0, 0);
            }
        }

        // min update: score = esq + acc ; ascending-k scan keeps first-occurrence ties
#pragma unroll
        for (int rf = 0; rf < 2; ++rf)
#pragma unroll
            for (int cf = 0; cf < 4; ++cf) {
                int kidx = ct * 64 + cf * 16 + (l & 15);
#pragma unroll
                for (int r = 0; r < 4; ++r) {
                    float v = ecf[cf] + acc[rf][cf][r];
                    if (v < minv[rf][r]) { minv[rf][r] = v; mini[rf][r] = kidx; }
                }
            }

        if (ct < 63) WRITE_LDS(p ^ 1);
        __syncthreads();
        if (ct < 62) STAGE_REGS(ct + 2);
    }

    // ---- argmin reduce across the 16 col-lanes (low 4 lane bits) ----
#pragma unroll
    for (int off = 1; off < 16; off <<= 1) {
#pragma unroll
        for (int rf = 0; rf < 2; ++rf)
#pragma unroll
            for (int r = 0; r < 4; ++r) {
                float v2 = __shfl_xor(minv[rf][r], off);
                int   i2 = __shfl_xor(mini[rf][r], off);
                if (v2 < minv[rf][r] || (v2 == minv[rf][r] && i2 < mini[rf][r])) {
                    minv[rf][r] = v2; mini[rf][r] = i2;
                }
            }
    }
    if ((l & 15) == 0) {
#pragma unroll
        for (int rf = 0; rf < 2; ++rf)
#pragma unroll
            for (int r = 0; r < 4; ++r) {
                int row = w * 32 + rf * 16 + (l >> 4) * 4 + r;   // C/D: row=(l>>4)*4+reg (m89)
                int k   = mini[rf][r];
                idx_s[row] = k;
                out_idx[row0 + row] = (float)k;
                atomicAdd(&ncs_acc[k], 1.0f);
            }
    }
    __syncthreads();

    // ---- fused epilogue: gather quantize, commit-loss partial, embed_sum scatter ----
    {
        const float4* xg = (const float4*)(x + (size_t)row0 * DIM);
        const float4* eg = (const float4*)embed;
        float4* qg = ((float4*)out_q) + (size_t)row0 * 32;
        float lsum = 0.f;
#pragma unroll 4
        for (int it = 0; it < 16; ++it) {
            int i4 = tid + it * 256;
            int r = i4 >> 5, c4 = i4 & 31;
            int k = idx_s[r];
            float4 q  = eg[k * 32 + c4];
            float4 xv = xg[i4];
            qg[i4] = q;
            float d0 = q.x - xv.x, d1 = q.y - xv.y, d2 = q.z - xv.z, d3 = q.w - xv.w;
            lsum += d0 * d0 + d1 * d1 + d2 * d2 + d3 * d3;
            float* ea = emb_acc + (size_t)k * DIM + c4 * 4;
            atomicAdd(ea + 0, xv.x); atomicAdd(ea + 1, xv.y);
            atomicAdd(ea + 2, xv.z); atomicAdd(ea + 3, xv.w);
        }
        red[tid] = lsum;
    }
    __syncthreads();
    for (int s = 128; s >= 1; s >>= 1) {
        if (tid < s) red[tid] += red[tid + s];
        __syncthreads();
    }
    if (tid == 0) atomicAdd(loss_p, red[0]);
}

// ---------------- finalize cluster sizes, n_total, inv_smoothed, loss scale ----------------
__global__ __launch_bounds__(256) void vq_finalize_kernel(const float* __restrict__ cs,
                                                          float* __restrict__ out,
                                                          float* __restrict__ inv_sm) {
    __shared__ float red[256];
    float* ncs    = out + OFF_NCS;
    float* loss_p = out + OFF_LOSS;
    int tid = threadIdx.x;
    float vloc[16];
    float part = 0.f;
#pragma unroll
    for (int it = 0; it < 16; ++it) {
        int k = tid + it * 256;
        float v = fmaf(cs[k], DECAY_F, ncs[k] * ONE_MINUS_DECAY);
        vloc[it] = v;
        ncs[k] = v;
        part += v;
    }
    red[tid] = part;
    __syncthreads();
    for (int s = 128; s >= 1; s >>= 1) {
        if (tid < s) red[tid] += red[tid + s];
        __syncthreads();
    }
    float ntot = red[0];
    float num  = ntot + (float)KCODES * EPS_F;
#pragma unroll
    for (int it = 0; it < 16; ++it) {
        int k = tid + it * 256;
        inv_sm[k] = num / ((vloc[it] + EPS_F) * ntot);
    }
    if (tid == 0) loss_p[0] = loss_p[0] * (1.0f / ((float)NPTS * (float)DIM));
}

// ---------------- new_embed = (embed_avg*0.99 + embed_sum*0.01) / smoothed ----------------
__global__ __launch_bounds__(256) void vq_embed_kernel(const float* __restrict__ eavg,
                                                       const float* __restrict__ inv_sm,
                                                       float* __restrict__ out) {
    float* emb = out + OFF_EMB;
    int i = blockIdx.x * 256 + threadIdx.x;
    int k = i >> 7;
    float v = fmaf(eavg[i], DECAY_F, emb[i] * ONE_MINUS_DECAY);
    emb[i] = v * inv_sm[k];
}

extern "C" void kernel_launch(void* const* d_in, const int* in_sizes, int n_in,
                              void* d_out, int out_size, void* d_ws, size_t ws_size,
                              hipStream_t stream) {
    const float* x     = (const float*)d_in[0];
    const float* embed = (const float*)d_in[1];
    const float* cs    = (const float*)d_in[2];
    const float* eavg  = (const float*)d_in[3];
    float* out = (float*)d_out;

    // ws layout: esq[K] f32 | inv_sm[K] f32 | Ehi[K*D] f16 | Elo[K*D] f16  (~2.1 MB)
    float*     esq    = (float*)d_ws;
    float*     inv_sm = esq + KCODES;
    _Float16*  Ehi    = (_Float16*)(inv_sm + KCODES);
    _Float16*  Elo    = Ehi + (size_t)KCODES * DIM;

    hipMemsetAsync(out + OFF_LOSS, 0, (size_t)(1 + KCODES * DIM + KCODES) * sizeof(float), stream);

    vq_prep_kernel<<<KCODES / 4, 256, 0, stream>>>(embed, esq, Ehi, Elo);
    vq_main_kernel<<<NPTS / 128, 256, 0, stream>>>(x, embed, esq, Ehi, Elo, out);
    vq_finalize_kernel<<<1, 256, 0, stream>>>(cs, out, inv_sm);
    vq_embed_kernel<<<(KCODES * DIM) / 256, 256, 0, stream>>>(eavg, inv_sm, out);
}